// Round 2
// baseline (948.992 us; speedup 1.0000x reference)
//
#include <hip/hip_runtime.h>
#include <math.h>

#define NB 16
#define NC 48
#define NT 96
#define NP 12
#define NFF 64
#define CT 4608          // NC*NT
#define STEPS 7
#define NBLK 576         // 576 blocks * 4 waves = 2304 waves = 9216 rows / 4
#define NTHR 256

// ---- device-scope grid barrier state (zero-init at module load) ----
__device__ unsigned g_cnt = 0;
__device__ unsigned g_gen = 0;

__device__ __forceinline__ void gridbar(unsigned target) {
    __syncthreads();
    if (threadIdx.x == 0) {
        unsigned old = __hip_atomic_fetch_add(&g_cnt, 1u, __ATOMIC_ACQ_REL,
                                              __HIP_MEMORY_SCOPE_AGENT);
        if (old == NBLK - 1) {
            __hip_atomic_store(&g_cnt, 0u, __ATOMIC_RELAXED, __HIP_MEMORY_SCOPE_AGENT);
            __hip_atomic_fetch_add(&g_gen, 1u, __ATOMIC_RELEASE, __HIP_MEMORY_SCOPE_AGENT);
        } else {
            while ((int)(__hip_atomic_load(&g_gen, __ATOMIC_ACQUIRE,
                                           __HIP_MEMORY_SCOPE_AGENT) - target) < 0)
                __builtin_amdgcn_s_sleep(2);
        }
    }
    __syncthreads();
}

// ---- exact-GELU via Abramowitz-Stegun 7.1.26 erf (|abs err| <= 1.5e-7) ----
__device__ __forceinline__ float erf_fast(float x) {
    float a = fabsf(x);
    float t = __builtin_amdgcn_rcpf(fmaf(0.3275911f, a, 1.0f));
    float p = t * fmaf(t, fmaf(t, fmaf(t, fmaf(t, 1.061405429f, -1.453152027f),
                                       1.421413741f), -0.284496736f), 0.254829592f);
    float E = __builtin_amdgcn_exp2f(-a * a * 1.4426950408889634f);
    float y = fmaf(-p, E, 1.0f);
    return copysignf(y, x);
}
__device__ __forceinline__ float gelu_exact(float u) {
    float e  = erf_fast(u * 0.70710678118654752f);
    float hu = 0.5f * u;
    return fmaf(hu, e, hu);
}

// insert candidate (ev,ej) into sorted top-3 (v0,j0)>=(v1,j1)>=(v2,j2)
// ordering: value desc, index asc on ties (matches jax.lax.top_k)
#define INSERT3(ev, ej)                                                   \
    {                                                                     \
        bool w0_ = (ev > v0) || (ev == v0 && ej < j0);                    \
        bool w1_ = (ev > v1) || (ev == v1 && ej < j1);                    \
        bool w2_ = (ev > v2) || (ev == v2 && ej < j2);                    \
        if (w0_)      { v2 = v1; j2 = j1; v1 = v0; j1 = j0; v0 = ev; j0 = ej; } \
        else if (w1_) { v2 = v1; j2 = j1; v1 = ev; j1 = ej; }             \
        else if (w2_) { v2 = ev; j2 = ej; }                               \
    }

#define CSWAP(va, ja, vb, jb)                                             \
    {                                                                     \
        bool sw_ = (vb > va) || (vb == va && jb < ja);                    \
        float ov_ = va; int oj_ = ja;                                     \
        va = sw_ ? vb : va; ja = sw_ ? jb : ja;                           \
        vb = sw_ ? ov_ : vb; jb = sw_ ? oj_ : jb;                        \
    }

__global__ __launch_bounds__(NTHR, 3) void fused_kernel(
    const float* __restrict__ x,
    const float* __restrict__ g0, const float* __restrict__ b0,
    const float* __restrict__ g1, const float* __restrict__ b1,
    const float* __restrict__ g2, const float* __restrict__ b2,
    const float* __restrict__ Wagg, const float* __restrict__ bagg,
    const float* __restrict__ W1, const float* __restrict__ bm1,
    const float* __restrict__ W2, const float* __restrict__ wmsg,
    const float* __restrict__ bmsg,
    float* __restrict__ t_ws, float* __restrict__ res_ws,
    float* __restrict__ out)
{
    const int tid = threadIdx.x;
    const int bk  = blockIdx.x;
    const unsigned gen0 = __hip_atomic_load(&g_gen, __ATOMIC_RELAXED,
                                            __HIP_MEMORY_SCOPE_AGENT);
    unsigned nbar = 0;

    __shared__ float  xnL[NB][NT + 1];   // +1 pad: stride 96 would be 16-way bank conflict
    __shared__ float  shB[NB * NP];
    __shared__ float  wagg[NP * NP];
    __shared__ float4 coef[NFF];

    if (tid < NFF) coef[tid] = make_float4(W1[2 * tid], W1[2 * tid + 1], bm1[tid], W2[tid]);
    const float wmsg0 = wmsg[0], bmsg0 = bmsg[0];

    // ---- per-thread phase1 constants (blocks < 48 only) ----
    const int p1_p = tid >> 4;          // p in [0,12) for tid<192
    const int p1_b = tid & 15;          // b in [0,16)
    float g1v = 0.f, b1v = 0.f, g2v = 0.f, b2v = 0.f, baggv = 0.f;
    if (bk < NC) {
        if (tid < NP * NP) wagg[tid] = Wagg[tid];
        if (tid < 192) {
            g1v = g1[bk * NP + p1_p]; b1v = b1[bk * NP + p1_p];
            g2v = g2[bk * NP + p1_p]; b2v = b2[bk * NP + p1_p];
            baggv = bagg[p1_p];
        }
        // ---- BN0 for this channel: fills xnL + writes 'first' out slice ----
        if (tid < NT) {
            const int tt = tid;
            float v[NB]; float sum = 0.f;
#pragma unroll
            for (int b = 0; b < NB; b++) { v[b] = x[b * CT + bk * NT + tt]; sum += v[b]; }
            float mu = sum * (1.f / NB);
            float var = 0.f;
#pragma unroll
            for (int b = 0; b < NB; b++) { float d = v[b] - mu; var = fmaf(d, d, var); }
            var *= (1.f / NB);
            float rs = rsqrtf(var + 1e-5f);
            float gg = g0[bk * NT + tt], bb = b0[bk * NT + tt];
#pragma unroll
            for (int b = 0; b < NB; b++) {
                float y = (v[b] - mu) * rs * gg + bb;
                xnL[b][tt] = y;
                if (tt < NP) out[(b * NC + bk) * NT + tt] = y;
            }
        }
    }
    __syncthreads();

    // ---- per-thread edge constants ----
    const int w    = bk * 4 + (tid >> 6);       // wave id in [0,2304)
    const int lane = tid & 63;
    const int rl   = lane >> 4;                 // row within the wave's 4-row group
    const int jg   = lane & 15;                 // j-lane in [0,16)
    const int e_bp = w / NP;                    // (b,p) pair in [0,192)
    const int e_i  = (w - e_bp * NP) * 4 + rl;  // i in [0,48)
    const int e_b  = e_bp / NP, e_p = e_bp - e_b * NP;
    const float* tb = t_ws + e_bp * NC;
    const int outIdxBase = (e_b * NC + e_i) * NT + e_p;
    const int resIdx     = (e_b * NC + e_i) * NP + e_p;

    for (int s = 0; s < STEPS; s++) {
        // ================= phase 1: BN1 -> agg+gelu -> +xw -> BN2 =================
        if (bk < NC && tid < 192) {
            const int b = p1_b, p = p1_p, c = bk;
            float v = (s == 0) ? xnL[b][p] : out[(b * NC + c) * NT + NP * s + p];
            // BN1 over b: 16-lane butterfly (lanes of a group share p)
            float s1 = v;
#pragma unroll
            for (int off = 1; off < 16; off <<= 1) s1 += __shfl_xor(s1, off);
            float mu = s1 * (1.f / NB);
            float d  = v - mu;
            float q  = d * d;
#pragma unroll
            for (int off = 1; off < 16; off <<= 1) q += __shfl_xor(q, off);
            float var = q * (1.f / NB);
            float inp = d * rsqrtf(var + 1e-5f) * g1v + b1v;
            shB[b * NP + p] = inp;
        }
        __syncthreads();
        if (bk < NC && tid < 192) {
            const int b = p1_b, p = p1_p, c = bk;
            float acc = baggv;
#pragma unroll
            for (int pp = 0; pp < NP; pp++)
                acc = fmaf(shB[b * NP + pp], wagg[p * NP + pp], acc);
            float res = gelu_exact(acc) + xnL[b][NP + NP * s + p];
            res_ws[(b * NC + c) * NP + p] = res;
            // BN2 over b: butterfly again
            float s2 = res;
#pragma unroll
            for (int off = 1; off < 16; off <<= 1) s2 += __shfl_xor(s2, off);
            float mu2 = s2 * (1.f / NB);
            float d2  = res - mu2;
            float q2  = d2 * d2;
#pragma unroll
            for (int off = 1; off < 16; off <<= 1) q2 += __shfl_xor(q2, off);
            float var2 = q2 * (1.f / NB);
            float t = d2 * rsqrtf(var2 + 1e-5f) * g2v + b2v;
            t_ws[(b * NP + p) * NC + c] = t;    // t[b][p][c]
        }
        gridbar(gen0 + ++nbar);

        // ======== edge MLP + top-3 + softmax + message (all 576 blocks) ========
        {
            float zi  = tb[e_i];
            float zj0 = tb[jg], zj1 = tb[jg + 16], zj2 = tb[jg + 32];
            float e0 = 0.f, e1 = 0.f, e2 = 0.f;
#pragma unroll 8
            for (int ff = 0; ff < NFF; ff++) {
                float4 cf = coef[ff];
                float base = fmaf(cf.x, zi, cf.z);
                e0 = fmaf(gelu_exact(fmaf(cf.y, zj0, base)), cf.w, e0);
                e1 = fmaf(gelu_exact(fmaf(cf.y, zj1, base)), cf.w, e1);
                e2 = fmaf(gelu_exact(fmaf(cf.y, zj2, base)), cf.w, e2);
            }
            // local sort-3 (value desc, index asc)
            float v0 = e0, v1 = e1, v2 = e2;
            int   j0 = jg, j1 = jg + 16, j2 = jg + 32;
            CSWAP(v0, j0, v1, j1);
            CSWAP(v1, j1, v2, j2);
            CSWAP(v0, j0, v1, j1);
            // butterfly merge across the 16 j-lanes -> every lane holds row top-3
#pragma unroll
            for (int off = 1; off < 16; off <<= 1) {
                float o0 = __shfl_xor(v0, off), o1 = __shfl_xor(v1, off), o2 = __shfl_xor(v2, off);
                int   q0 = __shfl_xor(j0, off), q1 = __shfl_xor(j1, off), q2 = __shfl_xor(j2, off);
                INSERT3(o0, q0);
                INSERT3(o1, q1);
                INSERT3(o2, q2);
            }
            // softmax over the 3 selected (max = v0); znew = wmsg*avg(t) + bmsg
            const float L2E = 1.4426950408889634f;
            float ww1 = __builtin_amdgcn_exp2f((v1 - v0) * L2E);
            float ww2 = __builtin_amdgcn_exp2f((v2 - v0) * L2E);
            float wsum = 1.f + ww1 + ww2;
            float tsum = fmaf(ww2, tb[j2], fmaf(ww1, tb[j1], tb[j0]));
            float znew = fmaf(wmsg0, tsum / wsum, bmsg0);
            if (jg == 0) {
                float res = res_ws[resIdx];
                out[outIdxBase + NP * (s + 1)] = fmaf(0.5f, znew, res);  // ALPHA=0.5
            }
        }
        if (s < STEPS - 1) gridbar(gen0 + ++nbar);
    }
}

extern "C" void kernel_launch(void* const* d_in, const int* in_sizes, int n_in,
                              void* d_out, int out_size, void* d_ws, size_t ws_size,
                              hipStream_t stream)
{
    const float* x    = (const float*)d_in[0];
    const float* g0   = (const float*)d_in[1];
    const float* b0   = (const float*)d_in[2];
    const float* g1   = (const float*)d_in[3];
    const float* b1   = (const float*)d_in[4];
    const float* g2   = (const float*)d_in[5];
    const float* b2   = (const float*)d_in[6];
    const float* Wagg = (const float*)d_in[7];
    const float* bagg = (const float*)d_in[8];
    const float* W1   = (const float*)d_in[9];
    const float* bm1  = (const float*)d_in[10];
    const float* W2   = (const float*)d_in[11];
    // d_in[12] = bm2: uniform shift of e -> invariant under top-k & softmax; unused
    const float* wmsg = (const float*)d_in[13];
    const float* bmsg = (const float*)d_in[14];
    float* out = (float*)d_out;

    float* t_ws   = (float*)d_ws;            // 9216 floats
    float* res_ws = t_ws + (NB * NP * NC);   // 9216 floats

    fused_kernel<<<dim3(NBLK), dim3(NTHR), 0, stream>>>(
        x, g0, b0, g1, b1, g2, b2, Wagg, bagg, W1, bm1, W2, wmsg, bmsg,
        t_ws, res_ws, out);
}

// Round 3
// 547.037 us; speedup vs baseline: 1.7348x; 1.7348x over previous
//
#include <hip/hip_runtime.h>
#include <math.h>

#define NB 16
#define NC 48
#define NT 96
#define NP 12
#define NFF 64
#define CT 4608          // NC*NT
#define STEPS 7
#define NEDGE 576        // edge blocks: 576*4 waves = 2304 = 9216 rows / 4
#define NP1 48           // dedicated phase1 blocks (one per channel c)
#define NBLK (NEDGE + NP1)   // 624 total; <= 256 CUs * 3 blocks/CU = 768 resident
#define NTHR 256

// ---- device-scope grid barrier state (zero-init at module load) ----
// Relative-target scheme: each block reads g_gen at entry (quiescent value —
// the first bump, B(0), requires ALL 624 arrivals, so no bump can precede any
// block's entry read). Gens accumulate monotonically across launches.
__device__ unsigned g_cnt = 0;
__device__ unsigned g_gen = 0;

__device__ __forceinline__ void bar_arrive(unsigned threshold, unsigned target) {
    // tid==0 only, after __syncthreads(); ACQ_REL RMW = release (L2 writeback)
    unsigned old = __hip_atomic_fetch_add(&g_cnt, 1u, __ATOMIC_ACQ_REL,
                                          __HIP_MEMORY_SCOPE_AGENT);
    if (old == threshold - 1u) {
        __hip_atomic_store(&g_cnt, 0u, __ATOMIC_RELAXED, __HIP_MEMORY_SCOPE_AGENT);
        __hip_atomic_store(&g_gen, target, __ATOMIC_RELEASE, __HIP_MEMORY_SCOPE_AGENT);
    }
}
__device__ __forceinline__ void bar_wait(unsigned target) {
    // RELAXED poll (no per-iteration cache invalidation!), one acquire fence after
    while ((int)(__hip_atomic_load(&g_gen, __ATOMIC_RELAXED,
                                   __HIP_MEMORY_SCOPE_AGENT) - target) < 0)
        __builtin_amdgcn_s_sleep(4);
    __builtin_amdgcn_fence(__ATOMIC_ACQUIRE, "agent");
}

// ---- exact-GELU via Abramowitz-Stegun 7.1.26 erf (|abs err| <= 1.5e-7) ----
__device__ __forceinline__ float erf_fast(float x) {
    float a = fabsf(x);
    float t = __builtin_amdgcn_rcpf(fmaf(0.3275911f, a, 1.0f));
    float p = t * fmaf(t, fmaf(t, fmaf(t, fmaf(t, 1.061405429f, -1.453152027f),
                                       1.421413741f), -0.284496736f), 0.254829592f);
    float E = __builtin_amdgcn_exp2f(-a * a * 1.4426950408889634f);
    float y = fmaf(-p, E, 1.0f);
    return copysignf(y, x);
}
__device__ __forceinline__ float gelu_exact(float u) {
    float e  = erf_fast(u * 0.70710678118654752f);
    float hu = 0.5f * u;
    return fmaf(hu, e, hu);
}

// insert candidate (ev,ej) into sorted top-3; value desc, index asc on ties
#define INSERT3(ev, ej)                                                   \
    {                                                                     \
        bool w0_ = (ev > v0) || (ev == v0 && ej < j0);                    \
        bool w1_ = (ev > v1) || (ev == v1 && ej < j1);                    \
        bool w2_ = (ev > v2) || (ev == v2 && ej < j2);                    \
        if (w0_)      { v2 = v1; j2 = j1; v1 = v0; j1 = j0; v0 = ev; j0 = ej; } \
        else if (w1_) { v2 = v1; j2 = j1; v1 = ev; j1 = ej; }             \
        else if (w2_) { v2 = ev; j2 = ej; }                               \
    }

#define CSWAP(va, ja, vb, jb)                                             \
    {                                                                     \
        bool sw_ = (vb > va) || (vb == va && jb < ja);                    \
        float ov_ = va; int oj_ = ja;                                     \
        va = sw_ ? vb : va; ja = sw_ ? jb : ja;                           \
        vb = sw_ ? ov_ : vb; jb = sw_ ? oj_ : jb;                        \
    }

// Barrier/generation map (relative to gen0), 13 bumps per launch:
//   B(0): th=624, target 1      (doubles as entry handshake)
//   A(s): th=576, target 2s+2   (post-edge;  waiters: 48 phase1 blocks)
//   B(s): th=48,  target 2s+1   (post-phase1; waiters: 576 edge blocks), s>=1
__global__ __launch_bounds__(NTHR, 3) void fused_kernel(
    const float* __restrict__ x,
    const float* __restrict__ g0, const float* __restrict__ b0,
    const float* __restrict__ g1, const float* __restrict__ b1,
    const float* __restrict__ g2, const float* __restrict__ b2,
    const float* __restrict__ Wagg, const float* __restrict__ bagg,
    const float* __restrict__ W1, const float* __restrict__ bm1,
    const float* __restrict__ W2, const float* __restrict__ wmsg,
    const float* __restrict__ bmsg,
    float* __restrict__ t_ws, float* __restrict__ res_ws,
    float* __restrict__ out)
{
    const int tid = threadIdx.x;
    const int bk  = blockIdx.x;

    __shared__ float  xnL[NB][NT + 1];   // phase1 blocks only
    __shared__ float  shB[NB * NP];
    __shared__ float  wagg[NP * NP];
    __shared__ float4 coef[NFF];         // edge blocks only

    unsigned gen0 = 0;
    if (tid == 0)
        gen0 = __hip_atomic_load(&g_gen, __ATOMIC_RELAXED, __HIP_MEMORY_SCOPE_AGENT);

    if (bk >= NEDGE) {
        // ==================== dedicated phase1 block: c = bk - NEDGE ====================
        const int c = bk - NEDGE;
        const int p = tid >> 4;          // p in [0,12) for tid<192
        const int b = tid & 15;          // b in [0,16)
        float g1v = 0.f, b1v = 0.f, g2v = 0.f, b2v = 0.f, baggv = 0.f;
        if (tid < NP * NP) wagg[tid] = Wagg[tid];
        if (tid < 192) {
            g1v = g1[c * NP + p]; b1v = b1[c * NP + p];
            g2v = g2[c * NP + p]; b2v = b2[c * NP + p];
            baggv = bagg[p];
        }
        // BN0 for this channel -> xnL; write 'first' slice to out
        if (tid < NT) {
            const int tt = tid;
            float v[NB]; float sum = 0.f;
#pragma unroll
            for (int bb = 0; bb < NB; bb++) { v[bb] = x[bb * CT + c * NT + tt]; sum += v[bb]; }
            float mu = sum * (1.f / NB);
            float var = 0.f;
#pragma unroll
            for (int bb = 0; bb < NB; bb++) { float d = v[bb] - mu; var = fmaf(d, d, var); }
            var *= (1.f / NB);
            float rs = rsqrtf(var + 1e-5f);
            float gg = g0[c * NT + tt], bbv = b0[c * NT + tt];
#pragma unroll
            for (int bb = 0; bb < NB; bb++) {
                float y = (v[bb] - mu) * rs * gg + bbv;
                xnL[bb][tt] = y;
                if (tt < NP) out[(bb * NC + c) * NT + tt] = y;
            }
        }
        __syncthreads();

        for (int s = 0; s < STEPS; s++) {
            if (s > 0) {
                if (tid == 0) bar_wait(gen0 + 2 * s);    // A(s-1): edge(s-1) done
                __syncthreads();
            }
            if (tid < 192) {
                float v = (s == 0) ? xnL[b][p] : out[(b * NC + c) * NT + NP * s + p];
                float s1 = v;
#pragma unroll
                for (int off = 1; off < 16; off <<= 1) s1 += __shfl_xor(s1, off);
                float mu = s1 * (1.f / NB);
                float d  = v - mu;
                float q  = d * d;
#pragma unroll
                for (int off = 1; off < 16; off <<= 1) q += __shfl_xor(q, off);
                float var = q * (1.f / NB);
                float inp = d * rsqrtf(var + 1e-5f) * g1v + b1v;
                shB[b * NP + p] = inp;
            }
            __syncthreads();
            if (tid < 192) {
                float acc = baggv;
#pragma unroll
                for (int pp = 0; pp < NP; pp++)
                    acc = fmaf(shB[b * NP + pp], wagg[p * NP + pp], acc);
                float res = gelu_exact(acc) + xnL[b][NP + NP * s + p];
                res_ws[(b * NC + c) * NP + p] = res;
                float s2 = res;
#pragma unroll
                for (int off = 1; off < 16; off <<= 1) s2 += __shfl_xor(s2, off);
                float mu2 = s2 * (1.f / NB);
                float d2  = res - mu2;
                float q2  = d2 * d2;
#pragma unroll
                for (int off = 1; off < 16; off <<= 1) q2 += __shfl_xor(q2, off);
                float var2 = q2 * (1.f / NB);
                float t = d2 * rsqrtf(var2 + 1e-5f) * g2v + b2v;
                t_ws[(b * NP + p) * NC + c] = t;    // t[b][p][c]
            }
            __syncthreads();
            if (tid == 0)
                bar_arrive(s == 0 ? NBLK : NP1, gen0 + (s == 0 ? 1 : 2 * s + 1)); // B(s)
        }
        return;
    }

    // ==================== edge block ====================
    if (tid < NFF) coef[tid] = make_float4(W1[2 * tid], W1[2 * tid + 1], bm1[tid], W2[tid]);
    const float wmsg0 = wmsg[0], bmsg0 = bmsg[0];

    const int w    = bk * 4 + (tid >> 6);       // wave id in [0,2304)
    const int lane = tid & 63;
    const int rl   = lane >> 4;                 // row within the wave's 4-row group
    const int jg   = lane & 15;                 // j-lane in [0,16)
    const int e_bp = w / NP;                    // (b,p) pair in [0,192)
    const int e_i  = (w - e_bp * NP) * 4 + rl;  // i in [0,48)
    const int e_b  = e_bp / NP, e_p = e_bp - e_b * NP;
    const float* tb = t_ws + e_bp * NC;
    const int outIdxBase = (e_b * NC + e_i) * NT + e_p;
    const int resIdx     = (e_b * NC + e_i) * NP + e_p;

    __syncthreads();
    if (tid == 0) bar_arrive(NBLK, gen0 + 1);   // entry handshake into B(0)

    for (int s = 0; s < STEPS; s++) {
        if (tid == 0) bar_wait(gen0 + (s == 0 ? 1 : 2 * s + 1));  // B(s): t_ws ready
        __syncthreads();

        float zi  = tb[e_i];
        float zj0 = tb[jg], zj1 = tb[jg + 16], zj2 = tb[jg + 32];
        float e0 = 0.f, e1 = 0.f, e2 = 0.f;
#pragma unroll 8
        for (int ff = 0; ff < NFF; ff++) {
            float4 cf = coef[ff];
            float base = fmaf(cf.x, zi, cf.z);
            e0 = fmaf(gelu_exact(fmaf(cf.y, zj0, base)), cf.w, e0);
            e1 = fmaf(gelu_exact(fmaf(cf.y, zj1, base)), cf.w, e1);
            e2 = fmaf(gelu_exact(fmaf(cf.y, zj2, base)), cf.w, e2);
        }
        // local sort-3 (value desc, index asc)
        float v0 = e0, v1 = e1, v2 = e2;
        int   j0 = jg, j1 = jg + 16, j2 = jg + 32;
        CSWAP(v0, j0, v1, j1);
        CSWAP(v1, j1, v2, j2);
        CSWAP(v0, j0, v1, j1);
        // butterfly merge across the 16 j-lanes -> every lane holds row top-3
#pragma unroll
        for (int off = 1; off < 16; off <<= 1) {
            float o0 = __shfl_xor(v0, off), o1 = __shfl_xor(v1, off), o2 = __shfl_xor(v2, off);
            int   q0 = __shfl_xor(j0, off), q1 = __shfl_xor(j1, off), q2 = __shfl_xor(j2, off);
            INSERT3(o0, q0);
            INSERT3(o1, q1);
            INSERT3(o2, q2);
        }
        // softmax over the 3 selected (max = v0); znew = wmsg*avg(t) + bmsg
        const float L2E = 1.4426950408889634f;
        float ww1 = __builtin_amdgcn_exp2f((v1 - v0) * L2E);
        float ww2 = __builtin_amdgcn_exp2f((v2 - v0) * L2E);
        float wsum = 1.f + ww1 + ww2;
        float tsum = fmaf(ww2, tb[j2], fmaf(ww1, tb[j1], tb[j0]));
        float znew = fmaf(wmsg0, tsum / wsum, bmsg0);
        if (jg == 0) {
            float res = res_ws[resIdx];
            out[outIdxBase + NP * (s + 1)] = fmaf(0.5f, znew, res);  // ALPHA=0.5
        }

        if (s < STEPS - 1) {
            __syncthreads();                     // drain out-stores of all waves
            if (tid == 0) bar_arrive(NEDGE, gen0 + 2 * s + 2);   // A(s)
        }
    }
}

extern "C" void kernel_launch(void* const* d_in, const int* in_sizes, int n_in,
                              void* d_out, int out_size, void* d_ws, size_t ws_size,
                              hipStream_t stream)
{
    const float* x    = (const float*)d_in[0];
    const float* g0   = (const float*)d_in[1];
    const float* b0   = (const float*)d_in[2];
    const float* g1   = (const float*)d_in[3];
    const float* b1   = (const float*)d_in[4];
    const float* g2   = (const float*)d_in[5];
    const float* b2   = (const float*)d_in[6];
    const float* Wagg = (const float*)d_in[7];
    const float* bagg = (const float*)d_in[8];
    const float* W1   = (const float*)d_in[9];
    const float* bm1  = (const float*)d_in[10];
    const float* W2   = (const float*)d_in[11];
    // d_in[12] = bm2: uniform shift of e -> invariant under top-k & softmax; unused
    const float* wmsg = (const float*)d_in[13];
    const float* bmsg = (const float*)d_in[14];
    float* out = (float*)d_out;

    float* t_ws   = (float*)d_ws;            // 9216 floats
    float* res_ws = t_ws + (NB * NP * NC);   // 9216 floats

    fused_kernel<<<dim3(NBLK), dim3(NTHR), 0, stream>>>(
        x, g0, b0, g1, b1, g2, b2, Wagg, bagg, W1, bm1, W2, wmsg, bmsg,
        t_ws, res_ws, out);
}

// Round 4
// 361.012 us; speedup vs baseline: 2.6287x; 1.5153x over previous
//
#include <hip/hip_runtime.h>
#include <math.h>

#define NB 16
#define NC 48
#define NT 96
#define NP 12
#define NFF 64
#define CT 4608          // NC*NT
#define STEPS 7
#define NEDGE 576        // edge blocks: 576*4 waves = 2304 = 9216 rows / 4
#define NP1 48           // dedicated phase1 blocks (one per channel c)
#define NBLK (NEDGE + NP1)   // 624 total; <= 256 CUs * 3 blocks/CU = 768 resident
#define NTHR 256

// ---- hierarchical grid barrier (arrival tree: 24 lanes x 128B + root) ----
// Same-line atomic RMWs serialize ~100ns each at the coherence point (measured:
// rounds 2/3 scale linearly with arrival count). Spreading arrivals over 24
// cache lines parallelizes them across LLC banks.
#define NLANE 24
#define LSTRIDE 32   // words => 128 B between sub-counters

__device__ unsigned g_subA[NLANE * LSTRIDE];   // zero-init at module load
__device__ unsigned g_subB[NLANE * LSTRIDE];
__device__ unsigned g_rootA = 0;
__device__ unsigned g_rootB = 0;
__device__ unsigned g_gen  = 0;

// HB chain: data writes -> ACQ_REL lane RMW -> lane-last's ACQ_REL root RMW ->
// final arriver's RELEASE gen store -> waiter ACQUIRE fence. Lane/root resets
// (relaxed stores) are ordered by the subsequent release RMW and covered by the
// same chain; consecutive uses of one tree are separated by the other barrier.
__device__ __forceinline__ void tree_arrive(unsigned* subs, unsigned* root,
                                            int lane, unsigned laneTh,
                                            unsigned target) {
    unsigned old = __hip_atomic_fetch_add(&subs[lane * LSTRIDE], 1u,
                                          __ATOMIC_ACQ_REL, __HIP_MEMORY_SCOPE_AGENT);
    if (old == laneTh - 1u) {
        __hip_atomic_store(&subs[lane * LSTRIDE], 0u, __ATOMIC_RELAXED,
                           __HIP_MEMORY_SCOPE_AGENT);
        unsigned r = __hip_atomic_fetch_add(root, 1u, __ATOMIC_ACQ_REL,
                                            __HIP_MEMORY_SCOPE_AGENT);
        if (r == NLANE - 1u) {
            __hip_atomic_store(root, 0u, __ATOMIC_RELAXED, __HIP_MEMORY_SCOPE_AGENT);
            __hip_atomic_store(&g_gen, target, __ATOMIC_RELEASE,
                               __HIP_MEMORY_SCOPE_AGENT);
        }
    }
}
__device__ __forceinline__ void bar_wait(unsigned target) {
    while ((int)(__hip_atomic_load(&g_gen, __ATOMIC_RELAXED,
                                   __HIP_MEMORY_SCOPE_AGENT) - target) < 0)
        __builtin_amdgcn_s_sleep(1);
    __builtin_amdgcn_fence(__ATOMIC_ACQUIRE, "agent");
}

// ---- exact-GELU via Abramowitz-Stegun 7.1.26 erf (|abs err| <= 1.5e-7) ----
__device__ __forceinline__ float erf_fast(float x) {
    float a = fabsf(x);
    float t = __builtin_amdgcn_rcpf(fmaf(0.3275911f, a, 1.0f));
    float p = t * fmaf(t, fmaf(t, fmaf(t, fmaf(t, 1.061405429f, -1.453152027f),
                                       1.421413741f), -0.284496736f), 0.254829592f);
    float E = __builtin_amdgcn_exp2f(-a * a * 1.4426950408889634f);
    float y = fmaf(-p, E, 1.0f);
    return copysignf(y, x);
}
__device__ __forceinline__ float gelu_exact(float u) {
    float e  = erf_fast(u * 0.70710678118654752f);
    float hu = 0.5f * u;
    return fmaf(hu, e, hu);
}

// insert candidate (ev,ej) into sorted top-3; value desc, index asc on ties
#define INSERT3(ev, ej)                                                   \
    {                                                                     \
        bool w0_ = (ev > v0) || (ev == v0 && ej < j0);                    \
        bool w1_ = (ev > v1) || (ev == v1 && ej < j1);                    \
        bool w2_ = (ev > v2) || (ev == v2 && ej < j2);                    \
        if (w0_)      { v2 = v1; j2 = j1; v1 = v0; j1 = j0; v0 = ev; j0 = ej; } \
        else if (w1_) { v2 = v1; j2 = j1; v1 = ev; j1 = ej; }             \
        else if (w2_) { v2 = ev; j2 = ej; }                               \
    }

#define CSWAP(va, ja, vb, jb)                                             \
    {                                                                     \
        bool sw_ = (vb > va) || (vb == va && jb < ja);                    \
        float ov_ = va; int oj_ = ja;                                     \
        va = sw_ ? vb : va; ja = sw_ ? jb : ja;                           \
        vb = sw_ ? ov_ : vb; jb = sw_ ? oj_ : jb;                        \
    }

// Barrier/generation map (relative to gen0), 13 bumps per launch:
//   B(0): tree B, laneTh 26 (all 624 blocks), target 1   (entry handshake)
//   B(s): tree B, laneTh 2  (48 phase1 blocks), target 2s+1, s>=1
//   A(s): tree A, laneTh 24 (576 edge blocks),  target 2s+2
__global__ __launch_bounds__(NTHR, 3) void fused_kernel(
    const float* __restrict__ x,
    const float* __restrict__ g0, const float* __restrict__ b0,
    const float* __restrict__ g1, const float* __restrict__ b1,
    const float* __restrict__ g2, const float* __restrict__ b2,
    const float* __restrict__ Wagg, const float* __restrict__ bagg,
    const float* __restrict__ W1, const float* __restrict__ bm1,
    const float* __restrict__ W2, const float* __restrict__ wmsg,
    const float* __restrict__ bmsg,
    float* __restrict__ t_ws, float* __restrict__ res_ws,
    float* __restrict__ out)
{
    const int tid = threadIdx.x;
    const int bk  = blockIdx.x;
    const int lane24 = bk % NLANE;

    __shared__ float  xnL[NB][NT + 1];   // phase1 blocks only
    __shared__ float  shB[NB * NP];
    __shared__ float  wagg[NP * NP];
    __shared__ float4 coef[NFF];         // edge blocks only

    unsigned gen0 = 0;
    if (tid == 0)
        gen0 = __hip_atomic_load(&g_gen, __ATOMIC_RELAXED, __HIP_MEMORY_SCOPE_AGENT);

    if (bk >= NEDGE) {
        // ==================== dedicated phase1 block: c = bk - NEDGE ====================
        const int c = bk - NEDGE;
        const int p = tid >> 4;          // p in [0,12) for tid<192
        const int b = tid & 15;          // b in [0,16)
        float g1v = 0.f, b1v = 0.f, g2v = 0.f, b2v = 0.f, baggv = 0.f;
        if (tid < NP * NP) wagg[tid] = Wagg[tid];
        if (tid < 192) {
            g1v = g1[c * NP + p]; b1v = b1[c * NP + p];
            g2v = g2[c * NP + p]; b2v = b2[c * NP + p];
            baggv = bagg[p];
        }
        // BN0 for this channel -> xnL; write 'first' slice to out
        if (tid < NT) {
            const int tt = tid;
            float v[NB]; float sum = 0.f;
#pragma unroll
            for (int bb = 0; bb < NB; bb++) { v[bb] = x[bb * CT + c * NT + tt]; sum += v[bb]; }
            float mu = sum * (1.f / NB);
            float var = 0.f;
#pragma unroll
            for (int bb = 0; bb < NB; bb++) { float d = v[bb] - mu; var = fmaf(d, d, var); }
            var *= (1.f / NB);
            float rs = rsqrtf(var + 1e-5f);
            float gg = g0[c * NT + tt], bbv = b0[c * NT + tt];
#pragma unroll
            for (int bb = 0; bb < NB; bb++) {
                float y = (v[bb] - mu) * rs * gg + bbv;
                xnL[bb][tt] = y;
                if (tt < NP) out[(bb * NC + c) * NT + tt] = y;
            }
        }
        __syncthreads();

        for (int s = 0; s < STEPS; s++) {
            if (s > 0) {
                if (tid == 0) bar_wait(gen0 + 2 * s);    // A(s-1): edge(s-1) done
                __syncthreads();
            }
            if (tid < 192) {
                float v = (s == 0) ? xnL[b][p] : out[(b * NC + c) * NT + NP * s + p];
                float s1 = v;
#pragma unroll
                for (int off = 1; off < 16; off <<= 1) s1 += __shfl_xor(s1, off);
                float mu = s1 * (1.f / NB);
                float d  = v - mu;
                float q  = d * d;
#pragma unroll
                for (int off = 1; off < 16; off <<= 1) q += __shfl_xor(q, off);
                float var = q * (1.f / NB);
                float inp = d * rsqrtf(var + 1e-5f) * g1v + b1v;
                shB[b * NP + p] = inp;
            }
            __syncthreads();
            if (tid < 192) {
                float acc = baggv;
#pragma unroll
                for (int pp = 0; pp < NP; pp++)
                    acc = fmaf(shB[b * NP + pp], wagg[p * NP + pp], acc);
                float res = gelu_exact(acc) + xnL[b][NP + NP * s + p];
                res_ws[(b * NC + c) * NP + p] = res;
                float s2 = res;
#pragma unroll
                for (int off = 1; off < 16; off <<= 1) s2 += __shfl_xor(s2, off);
                float mu2 = s2 * (1.f / NB);
                float d2  = res - mu2;
                float q2  = d2 * d2;
#pragma unroll
                for (int off = 1; off < 16; off <<= 1) q2 += __shfl_xor(q2, off);
                float var2 = q2 * (1.f / NB);
                float t = d2 * rsqrtf(var2 + 1e-5f) * g2v + b2v;
                t_ws[(b * NP + p) * NC + c] = t;    // t[b][p][c]
            }
            __syncthreads();
            if (tid == 0)
                tree_arrive(g_subB, &g_rootB, lane24,
                            s == 0 ? 26u : 2u, gen0 + 2 * s + 1);   // B(s)
        }
        return;
    }

    // ==================== edge block ====================
    if (tid < NFF) coef[tid] = make_float4(W1[2 * tid], W1[2 * tid + 1], bm1[tid], W2[tid]);
    const float wmsg0 = wmsg[0], bmsg0 = bmsg[0];

    const int w    = bk * 4 + (tid >> 6);       // wave id in [0,2304)
    const int lane = tid & 63;
    const int rl   = lane >> 4;                 // row within the wave's 4-row group
    const int jg   = lane & 15;                 // j-lane in [0,16)
    const int e_bp = w / NP;                    // (b,p) pair in [0,192)
    const int e_i  = (w - e_bp * NP) * 4 + rl;  // i in [0,48)
    const int e_b  = e_bp / NP, e_p = e_bp - e_b * NP;
    const float* tb = t_ws + e_bp * NC;
    const int outIdxBase = (e_b * NC + e_i) * NT + e_p;
    const int resIdx     = (e_b * NC + e_i) * NP + e_p;

    __syncthreads();
    if (tid == 0)
        tree_arrive(g_subB, &g_rootB, lane24, 26u, gen0 + 1);  // entry into B(0)

    for (int s = 0; s < STEPS; s++) {
        if (tid == 0) bar_wait(gen0 + 2 * s + 1);  // B(s): t_ws ready
        __syncthreads();

        float zi  = tb[e_i];
        float zj0 = tb[jg], zj1 = tb[jg + 16], zj2 = tb[jg + 32];
        float e0 = 0.f, e1 = 0.f, e2 = 0.f;
#pragma unroll 8
        for (int ff = 0; ff < NFF; ff++) {
            float4 cf = coef[ff];
            float base = fmaf(cf.x, zi, cf.z);
            e0 = fmaf(gelu_exact(fmaf(cf.y, zj0, base)), cf.w, e0);
            e1 = fmaf(gelu_exact(fmaf(cf.y, zj1, base)), cf.w, e1);
            e2 = fmaf(gelu_exact(fmaf(cf.y, zj2, base)), cf.w, e2);
        }
        // local sort-3 (value desc, index asc)
        float v0 = e0, v1 = e1, v2 = e2;
        int   j0 = jg, j1 = jg + 16, j2 = jg + 32;
        CSWAP(v0, j0, v1, j1);
        CSWAP(v1, j1, v2, j2);
        CSWAP(v0, j0, v1, j1);
        // butterfly merge across the 16 j-lanes -> every lane holds row top-3
#pragma unroll
        for (int off = 1; off < 16; off <<= 1) {
            float o0 = __shfl_xor(v0, off), o1 = __shfl_xor(v1, off), o2 = __shfl_xor(v2, off);
            int   q0 = __shfl_xor(j0, off), q1 = __shfl_xor(j1, off), q2 = __shfl_xor(j2, off);
            INSERT3(o0, q0);
            INSERT3(o1, q1);
            INSERT3(o2, q2);
        }
        // softmax over the 3 selected (max = v0); znew = wmsg*avg(t) + bmsg
        const float L2E = 1.4426950408889634f;
        float ww1 = __builtin_amdgcn_exp2f((v1 - v0) * L2E);
        float ww2 = __builtin_amdgcn_exp2f((v2 - v0) * L2E);
        float wsum = 1.f + ww1 + ww2;
        float tsum = fmaf(ww2, tb[j2], fmaf(ww1, tb[j1], tb[j0]));
        float znew = fmaf(wmsg0, tsum / wsum, bmsg0);
        if (jg == 0) {
            float res = res_ws[resIdx];
            out[outIdxBase + NP * (s + 1)] = fmaf(0.5f, znew, res);  // ALPHA=0.5
        }

        if (s < STEPS - 1) {
            __syncthreads();                     // drain out-stores of all waves
            if (tid == 0)
                tree_arrive(g_subA, &g_rootA, lane24, 24u, gen0 + 2 * s + 2); // A(s)
        }
    }
}

extern "C" void kernel_launch(void* const* d_in, const int* in_sizes, int n_in,
                              void* d_out, int out_size, void* d_ws, size_t ws_size,
                              hipStream_t stream)
{
    const float* x    = (const float*)d_in[0];
    const float* g0   = (const float*)d_in[1];
    const float* b0   = (const float*)d_in[2];
    const float* g1   = (const float*)d_in[3];
    const float* b1   = (const float*)d_in[4];
    const float* g2   = (const float*)d_in[5];
    const float* b2   = (const float*)d_in[6];
    const float* Wagg = (const float*)d_in[7];
    const float* bagg = (const float*)d_in[8];
    const float* W1   = (const float*)d_in[9];
    const float* bm1  = (const float*)d_in[10];
    const float* W2   = (const float*)d_in[11];
    // d_in[12] = bm2: uniform shift of e -> invariant under top-k & softmax; unused
    const float* wmsg = (const float*)d_in[13];
    const float* bmsg = (const float*)d_in[14];
    float* out = (float*)d_out;

    float* t_ws   = (float*)d_ws;            // 9216 floats
    float* res_ws = t_ws + (NB * NP * NC);   // 9216 floats

    fused_kernel<<<dim3(NBLK), dim3(NTHR), 0, stream>>>(
        x, g0, b0, g1, b1, g2, b2, Wagg, bagg, W1, bm1, W2, wmsg, bmsg,
        t_ws, res_ws, out);
}

// Round 5
// 312.889 us; speedup vs baseline: 3.0330x; 1.1538x over previous
//
#include <hip/hip_runtime.h>
#include <math.h>

#define NB 16
#define NC 48
#define NT 96
#define NP 12
#define NFF 64
#define CT 4608          // NC*NT
#define STEPS 7
#define NEDGE 576        // edge blocks: 576*4 waves = 2304 = 9216 rows / 4
#define NP1 48           // dedicated phase1 blocks (one per channel c)
#define NBLK (NEDGE + NP1)   // 624 total; <= 256 CUs * 3 blocks/CU = 768 resident
#define NTHR 256

// ---- hierarchical grid barrier: 24-lane arrival tree + 24-word broadcast ----
// r3->r4 lesson: arrival RMW serialization was only part of the cost; the
// ~20us/barrier residual is poll contention — 576 agent-scope spin-loads on ONE
// LLC line saturate its bank. Fix: waiters poll per-group broadcast words
// (<=26 pollers/line); the finisher fans out 24 stores after one release fence.
#define NLANE 24
#define LSTRIDE 32   // words => 128 B between counters/words

__device__ unsigned g_subA[NLANE * LSTRIDE];   // zero-init at module load
__device__ unsigned g_subB[NLANE * LSTRIDE];
__device__ unsigned g_rootA = 0;
__device__ unsigned g_rootB = 0;
__device__ unsigned g_bcast[NLANE * LSTRIDE];

// HB chain: data writes -> ACQ_REL lane RMW -> lane-last ACQ_REL root RMW ->
// finisher release-fence -> bcast stores -> waiter poll + acquire fence.
// Counter resets (relaxed) precede the release fence => visible before reuse;
// tree reuse is separated by the opposite barrier's full chain.
__device__ __forceinline__ void tree_arrive(unsigned* subs, unsigned* root,
                                            int lane, unsigned laneTh,
                                            unsigned target) {
    unsigned old = __hip_atomic_fetch_add(&subs[lane * LSTRIDE], 1u,
                                          __ATOMIC_ACQ_REL, __HIP_MEMORY_SCOPE_AGENT);
    if (old == laneTh - 1u) {
        __hip_atomic_store(&subs[lane * LSTRIDE], 0u, __ATOMIC_RELAXED,
                           __HIP_MEMORY_SCOPE_AGENT);
        unsigned r = __hip_atomic_fetch_add(root, 1u, __ATOMIC_ACQ_REL,
                                            __HIP_MEMORY_SCOPE_AGENT);
        if (r == NLANE - 1u) {
            __hip_atomic_store(root, 0u, __ATOMIC_RELAXED, __HIP_MEMORY_SCOPE_AGENT);
            __builtin_amdgcn_fence(__ATOMIC_RELEASE, "agent");
#pragma unroll
            for (int g = 0; g < NLANE; g++)
                __hip_atomic_store(&g_bcast[g * LSTRIDE], target, __ATOMIC_RELAXED,
                                   __HIP_MEMORY_SCOPE_AGENT);
        }
    }
}
__device__ __forceinline__ void bar_wait(int grp, unsigned target) {
    while ((int)(__hip_atomic_load(&g_bcast[grp * LSTRIDE], __ATOMIC_RELAXED,
                                   __HIP_MEMORY_SCOPE_AGENT) - target) < 0)
        __builtin_amdgcn_s_sleep(2);
    __builtin_amdgcn_fence(__ATOMIC_ACQUIRE, "agent");
}

// ---- exact-GELU via Abramowitz-Stegun 7.1.26 erf (|abs err| <= 1.5e-7) ----
__device__ __forceinline__ float erf_fast(float x) {
    float a = fabsf(x);
    float t = __builtin_amdgcn_rcpf(fmaf(0.3275911f, a, 1.0f));
    float p = t * fmaf(t, fmaf(t, fmaf(t, fmaf(t, 1.061405429f, -1.453152027f),
                                       1.421413741f), -0.284496736f), 0.254829592f);
    float E = __builtin_amdgcn_exp2f(-a * a * 1.4426950408889634f);
    float y = fmaf(-p, E, 1.0f);
    return copysignf(y, x);
}
__device__ __forceinline__ float gelu_exact(float u) {
    float e  = erf_fast(u * 0.70710678118654752f);
    float hu = 0.5f * u;
    return fmaf(hu, e, hu);
}

// insert candidate (ev,ej) into sorted top-3; value desc, index asc on ties
#define INSERT3(ev, ej)                                                   \
    {                                                                     \
        bool w0_ = (ev > v0) || (ev == v0 && ej < j0);                    \
        bool w1_ = (ev > v1) || (ev == v1 && ej < j1);                    \
        bool w2_ = (ev > v2) || (ev == v2 && ej < j2);                    \
        if (w0_)      { v2 = v1; j2 = j1; v1 = v0; j1 = j0; v0 = ev; j0 = ej; } \
        else if (w1_) { v2 = v1; j2 = j1; v1 = ev; j1 = ej; }             \
        else if (w2_) { v2 = ev; j2 = ej; }                               \
    }

#define CSWAP(va, ja, vb, jb)                                             \
    {                                                                     \
        bool sw_ = (vb > va) || (vb == va && jb < ja);                    \
        float ov_ = va; int oj_ = ja;                                     \
        va = sw_ ? vb : va; ja = sw_ ? jb : ja;                           \
        vb = sw_ ? ov_ : vb; jb = sw_ ? oj_ : jb;                        \
    }

// Barrier map (targets relative to gen0 snapshot), 13 per launch:
//   B(0): tree B, laneTh 26 (all 624 blocks), target 1   (entry handshake)
//   B(s): tree B, laneTh 2  (48 phase1 blocks), target 2s+1, s>=1
//   A(s): tree A, laneTh 24 (576 edge blocks),  target 2s+2
__global__ __launch_bounds__(NTHR, 3) void fused_kernel(
    const float* __restrict__ x,
    const float* __restrict__ g0, const float* __restrict__ b0,
    const float* __restrict__ g1, const float* __restrict__ b1,
    const float* __restrict__ g2, const float* __restrict__ b2,
    const float* __restrict__ Wagg, const float* __restrict__ bagg,
    const float* __restrict__ W1, const float* __restrict__ bm1,
    const float* __restrict__ W2, const float* __restrict__ wmsg,
    const float* __restrict__ bmsg,
    float* __restrict__ t_ws, float* __restrict__ res_ws,
    float* __restrict__ out)
{
    const int tid = threadIdx.x;
    const int bk  = blockIdx.x;
    const int lane24 = bk % NLANE;   // arrival lane AND wait group

    __shared__ float  xnL[NB][NT + 1];   // phase1 blocks only
    __shared__ float  shB[NB * NP];
    __shared__ float  wagg[NP * NP];
    __shared__ float4 coef[NFF];         // edge blocks only

    unsigned gen0 = 0;
    if (tid == 0)
        gen0 = __hip_atomic_load(&g_bcast[lane24 * LSTRIDE], __ATOMIC_RELAXED,
                                 __HIP_MEMORY_SCOPE_AGENT);

    if (bk >= NEDGE) {
        // ==================== dedicated phase1 block: c = bk - NEDGE ====================
        const int c = bk - NEDGE;
        const int p = tid >> 4;          // p in [0,12) for tid<192
        const int b = tid & 15;          // b in [0,16)
        float g1v = 0.f, b1v = 0.f, g2v = 0.f, b2v = 0.f, baggv = 0.f;
        if (tid < NP * NP) wagg[tid] = Wagg[tid];
        if (tid < 192) {
            g1v = g1[c * NP + p]; b1v = b1[c * NP + p];
            g2v = g2[c * NP + p]; b2v = b2[c * NP + p];
            baggv = bagg[p];
        }
        // BN0 for this channel -> xnL; write 'first' slice to out
        if (tid < NT) {
            const int tt = tid;
            float v[NB]; float sum = 0.f;
#pragma unroll
            for (int bb = 0; bb < NB; bb++) { v[bb] = x[bb * CT + c * NT + tt]; sum += v[bb]; }
            float mu = sum * (1.f / NB);
            float var = 0.f;
#pragma unroll
            for (int bb = 0; bb < NB; bb++) { float d = v[bb] - mu; var = fmaf(d, d, var); }
            var *= (1.f / NB);
            float rs = rsqrtf(var + 1e-5f);
            float gg = g0[c * NT + tt], bbv = b0[c * NT + tt];
#pragma unroll
            for (int bb = 0; bb < NB; bb++) {
                float y = (v[bb] - mu) * rs * gg + bbv;
                xnL[bb][tt] = y;
                if (tt < NP) out[(bb * NC + c) * NT + tt] = y;
            }
        }
        __syncthreads();

        for (int s = 0; s < STEPS; s++) {
            if (s > 0) {
                if (tid == 0) bar_wait(lane24, gen0 + 2 * s);   // A(s-1)
                __syncthreads();
            }
            if (tid < 192) {
                float v = (s == 0) ? xnL[b][p] : out[(b * NC + c) * NT + NP * s + p];
                float s1 = v;
#pragma unroll
                for (int off = 1; off < 16; off <<= 1) s1 += __shfl_xor(s1, off);
                float mu = s1 * (1.f / NB);
                float d  = v - mu;
                float q  = d * d;
#pragma unroll
                for (int off = 1; off < 16; off <<= 1) q += __shfl_xor(q, off);
                float var = q * (1.f / NB);
                float inp = d * rsqrtf(var + 1e-5f) * g1v + b1v;
                shB[b * NP + p] = inp;
            }
            __syncthreads();
            if (tid < 192) {
                float acc = baggv;
#pragma unroll
                for (int pp = 0; pp < NP; pp++)
                    acc = fmaf(shB[b * NP + pp], wagg[p * NP + pp], acc);
                float res = gelu_exact(acc) + xnL[b][NP + NP * s + p];
                res_ws[(b * NC + c) * NP + p] = res;
                float s2 = res;
#pragma unroll
                for (int off = 1; off < 16; off <<= 1) s2 += __shfl_xor(s2, off);
                float mu2 = s2 * (1.f / NB);
                float d2  = res - mu2;
                float q2  = d2 * d2;
#pragma unroll
                for (int off = 1; off < 16; off <<= 1) q2 += __shfl_xor(q2, off);
                float var2 = q2 * (1.f / NB);
                float t = d2 * rsqrtf(var2 + 1e-5f) * g2v + b2v;
                t_ws[(b * NP + p) * NC + c] = t;    // t[b][p][c]
            }
            __syncthreads();
            if (tid == 0)
                tree_arrive(g_subB, &g_rootB, lane24,
                            s == 0 ? 26u : 2u, gen0 + 2 * s + 1);   // B(s)
        }
        return;
    }

    // ==================== edge block ====================
    if (tid < NFF) coef[tid] = make_float4(W1[2 * tid], W1[2 * tid + 1], bm1[tid], W2[tid]);
    const float wmsg0 = wmsg[0], bmsg0 = bmsg[0];

    const int w    = bk * 4 + (tid >> 6);       // wave id in [0,2304)
    const int lane = tid & 63;
    const int rl   = lane >> 4;                 // row within the wave's 4-row group
    const int jg   = lane & 15;                 // j-lane in [0,16)
    const int e_bp = w / NP;                    // (b,p) pair in [0,192)
    const int e_i  = (w - e_bp * NP) * 4 + rl;  // i in [0,48)
    const int e_b  = e_bp / NP, e_p = e_bp - e_b * NP;
    const float* tb = t_ws + e_bp * NC;
    const int outIdxBase = (e_b * NC + e_i) * NT + e_p;
    const int resIdx     = (e_b * NC + e_i) * NP + e_p;

    __syncthreads();
    if (tid == 0)
        tree_arrive(g_subB, &g_rootB, lane24, 26u, gen0 + 1);  // entry into B(0)

    for (int s = 0; s < STEPS; s++) {
        if (tid == 0) bar_wait(lane24, gen0 + 2 * s + 1);  // B(s): t_ws ready
        __syncthreads();

        float zi  = tb[e_i];
        float zj0 = tb[jg], zj1 = tb[jg + 16], zj2 = tb[jg + 32];
        float e0 = 0.f, e1 = 0.f, e2 = 0.f;
#pragma unroll 8
        for (int ff = 0; ff < NFF; ff++) {
            float4 cf = coef[ff];
            float base = fmaf(cf.x, zi, cf.z);
            e0 = fmaf(gelu_exact(fmaf(cf.y, zj0, base)), cf.w, e0);
            e1 = fmaf(gelu_exact(fmaf(cf.y, zj1, base)), cf.w, e1);
            e2 = fmaf(gelu_exact(fmaf(cf.y, zj2, base)), cf.w, e2);
        }
        // local sort-3 (value desc, index asc)
        float v0 = e0, v1 = e1, v2 = e2;
        int   j0 = jg, j1 = jg + 16, j2 = jg + 32;
        CSWAP(v0, j0, v1, j1);
        CSWAP(v1, j1, v2, j2);
        CSWAP(v0, j0, v1, j1);
        // butterfly merge across the 16 j-lanes -> every lane holds row top-3
#pragma unroll
        for (int off = 1; off < 16; off <<= 1) {
            float o0 = __shfl_xor(v0, off), o1 = __shfl_xor(v1, off), o2 = __shfl_xor(v2, off);
            int   q0 = __shfl_xor(j0, off), q1 = __shfl_xor(j1, off), q2 = __shfl_xor(j2, off);
            INSERT3(o0, q0);
            INSERT3(o1, q1);
            INSERT3(o2, q2);
        }
        // softmax over the 3 selected (max = v0); znew = wmsg*avg(t) + bmsg
        const float L2E = 1.4426950408889634f;
        float ww1 = __builtin_amdgcn_exp2f((v1 - v0) * L2E);
        float ww2 = __builtin_amdgcn_exp2f((v2 - v0) * L2E);
        float wsum = 1.f + ww1 + ww2;
        float tsum = fmaf(ww2, tb[j2], fmaf(ww1, tb[j1], tb[j0]));
        float znew = fmaf(wmsg0, tsum / wsum, bmsg0);
        if (jg == 0) {
            float res = res_ws[resIdx];
            out[outIdxBase + NP * (s + 1)] = fmaf(0.5f, znew, res);  // ALPHA=0.5
        }

        if (s < STEPS - 1) {
            __syncthreads();                     // drain out-stores of all waves
            if (tid == 0)
                tree_arrive(g_subA, &g_rootA, lane24, 24u, gen0 + 2 * s + 2); // A(s)
        }
    }
}

extern "C" void kernel_launch(void* const* d_in, const int* in_sizes, int n_in,
                              void* d_out, int out_size, void* d_ws, size_t ws_size,
                              hipStream_t stream)
{
    const float* x    = (const float*)d_in[0];
    const float* g0   = (const float*)d_in[1];
    const float* b0   = (const float*)d_in[2];
    const float* g1   = (const float*)d_in[3];
    const float* b1   = (const float*)d_in[4];
    const float* g2   = (const float*)d_in[5];
    const float* b2   = (const float*)d_in[6];
    const float* Wagg = (const float*)d_in[7];
    const float* bagg = (const float*)d_in[8];
    const float* W1   = (const float*)d_in[9];
    const float* bm1  = (const float*)d_in[10];
    const float* W2   = (const float*)d_in[11];
    // d_in[12] = bm2: uniform shift of e -> invariant under top-k & softmax; unused
    const float* wmsg = (const float*)d_in[13];
    const float* bmsg = (const float*)d_in[14];
    float* out = (float*)d_out;

    float* t_ws   = (float*)d_ws;            // 9216 floats
    float* res_ws = t_ws + (NB * NP * NC);   // 9216 floats

    fused_kernel<<<dim3(NBLK), dim3(NTHR), 0, stream>>>(
        x, g0, b0, g1, b1, g2, b2, Wagg, bagg, W1, bm1, W2, wmsg, bmsg,
        t_ws, res_ws, out);
}

// Round 6
// 247.734 us; speedup vs baseline: 3.8307x; 1.2630x over previous
//
#include <hip/hip_runtime.h>
#include <math.h>

#define NB 16
#define NC 48
#define NT 96
#define NP 12
#define NFF 64
#define CT 4608          // NC*NT
#define STEPS 7
#define NEDGE 576        // edge blocks: 576*4 waves = 2304 = 9216 rows / 4
#define NP1 48           // dedicated phase1 blocks (one per channel c)
#define NBLK (NEDGE + NP1)   // 624 total; <= 256 CUs * 3 blocks/CU = 768 resident
#define NTHR 256

// ---- fence-free grid barrier: 24-lane arrival tree + 24-word broadcast ----
// r5 post-mortem: the surviving ~14us/barrier was the L2 writeback/invalidate
// implicit in every agent-scope ACQ_REL/ACQUIRE (per-XCD L2 is not agent-
// coherent, so ordered atomics must flush it; ~624 wb + ~624 inv per round).
// Fix: ALL cross-block data uses relaxed agent-scope atomic ld/st (LLC-direct,
// L1/L2-bypassing — same class as the poll loads that provably see remote
// updates on this HW). Then ordering is free: __syncthreads drains each wave's
// vmcnt (stores complete AT LLC before tid0 arrives), the arrive->root->bcast
// chain is value-dependent, and waiter loads can't issue before the poll
// branch resolves. No fences anywhere.
#define NLANE 24
#define LSTRIDE 32   // words => 128 B between counters/words

__device__ unsigned g_subA[NLANE * LSTRIDE];   // zero-init at module load
__device__ unsigned g_subB[NLANE * LSTRIDE];
__device__ unsigned g_rootA = 0;
__device__ unsigned g_rootB = 0;
__device__ unsigned g_bcast[NLANE * LSTRIDE];

__device__ __forceinline__ void stg_llc(float* p, float v) {
    __hip_atomic_store(p, v, __ATOMIC_RELAXED, __HIP_MEMORY_SCOPE_AGENT);
}
__device__ __forceinline__ float ldg_llc(const float* p) {
    return __hip_atomic_load(p, __ATOMIC_RELAXED, __HIP_MEMORY_SCOPE_AGENT);
}

// Counter resets are relaxed: a tree is reused only after the OTHER barrier's
// full round (us-scale gap vs ns-scale store completion).
__device__ __forceinline__ void tree_arrive(unsigned* subs, unsigned* root,
                                            int lane, unsigned laneTh,
                                            unsigned target) {
    unsigned old = __hip_atomic_fetch_add(&subs[lane * LSTRIDE], 1u,
                                          __ATOMIC_RELAXED, __HIP_MEMORY_SCOPE_AGENT);
    if (old == laneTh - 1u) {
        __hip_atomic_store(&subs[lane * LSTRIDE], 0u, __ATOMIC_RELAXED,
                           __HIP_MEMORY_SCOPE_AGENT);
        unsigned r = __hip_atomic_fetch_add(root, 1u, __ATOMIC_RELAXED,
                                            __HIP_MEMORY_SCOPE_AGENT);
        if (r == NLANE - 1u) {
            __hip_atomic_store(root, 0u, __ATOMIC_RELAXED, __HIP_MEMORY_SCOPE_AGENT);
#pragma unroll
            for (int g = 0; g < NLANE; g++)
                __hip_atomic_store(&g_bcast[g * LSTRIDE], target, __ATOMIC_RELAXED,
                                   __HIP_MEMORY_SCOPE_AGENT);
        }
    }
}
__device__ __forceinline__ void bar_wait(int grp, unsigned target) {
    while ((int)(__hip_atomic_load(&g_bcast[grp * LSTRIDE], __ATOMIC_RELAXED,
                                   __HIP_MEMORY_SCOPE_AGENT) - target) < 0)
        __builtin_amdgcn_s_sleep(1);
    asm volatile("" ::: "memory");   // pin compiler: no load hoisting above the poll
}

// ---- exact-GELU via Abramowitz-Stegun 7.1.26 erf (|abs err| <= 1.5e-7) ----
__device__ __forceinline__ float erf_fast(float x) {
    float a = fabsf(x);
    float t = __builtin_amdgcn_rcpf(fmaf(0.3275911f, a, 1.0f));
    float p = t * fmaf(t, fmaf(t, fmaf(t, fmaf(t, 1.061405429f, -1.453152027f),
                                       1.421413741f), -0.284496736f), 0.254829592f);
    float E = __builtin_amdgcn_exp2f(-a * a * 1.4426950408889634f);
    float y = fmaf(-p, E, 1.0f);
    return copysignf(y, x);
}
__device__ __forceinline__ float gelu_exact(float u) {
    float e  = erf_fast(u * 0.70710678118654752f);
    float hu = 0.5f * u;
    return fmaf(hu, e, hu);
}

// insert candidate (ev,ej) into sorted top-3; value desc, index asc on ties
#define INSERT3(ev, ej)                                                   \
    {                                                                     \
        bool w0_ = (ev > v0) || (ev == v0 && ej < j0);                    \
        bool w1_ = (ev > v1) || (ev == v1 && ej < j1);                    \
        bool w2_ = (ev > v2) || (ev == v2 && ej < j2);                    \
        if (w0_)      { v2 = v1; j2 = j1; v1 = v0; j1 = j0; v0 = ev; j0 = ej; } \
        else if (w1_) { v2 = v1; j2 = j1; v1 = ev; j1 = ej; }             \
        else if (w2_) { v2 = ev; j2 = ej; }                               \
    }

#define CSWAP(va, ja, vb, jb)                                             \
    {                                                                     \
        bool sw_ = (vb > va) || (vb == va && jb < ja);                    \
        float ov_ = va; int oj_ = ja;                                     \
        va = sw_ ? vb : va; ja = sw_ ? jb : ja;                           \
        vb = sw_ ? ov_ : vb; jb = sw_ ? oj_ : jb;                        \
    }

// Barrier map (targets relative to gen0 snapshot), 13 per launch:
//   B(0): tree B, laneTh 26 (all 624 blocks), target 1   (entry handshake)
//   B(s): tree B, laneTh 2  (48 phase1 blocks), target 2s+1, s>=1
//   A(s): tree A, laneTh 24 (576 edge blocks),  target 2s+2
__global__ __launch_bounds__(NTHR, 3) void fused_kernel(
    const float* __restrict__ x,
    const float* __restrict__ g0, const float* __restrict__ b0,
    const float* __restrict__ g1, const float* __restrict__ b1,
    const float* __restrict__ g2, const float* __restrict__ b2,
    const float* __restrict__ Wagg, const float* __restrict__ bagg,
    const float* __restrict__ W1, const float* __restrict__ bm1,
    const float* __restrict__ W2, const float* __restrict__ wmsg,
    const float* __restrict__ bmsg,
    float* __restrict__ t_ws, float* __restrict__ res_ws,
    float* __restrict__ out)
{
    const int tid = threadIdx.x;
    const int bk  = blockIdx.x;
    const int lane24 = bk % NLANE;   // arrival lane AND wait group

    __shared__ float  xnL[NB][NT + 1];   // phase1 blocks only
    __shared__ float  shB[NB * NP];
    __shared__ float  wagg[NP * NP];
    __shared__ float4 coef[NFF];         // edge blocks only

    unsigned gen0 = 0;
    if (tid == 0)
        gen0 = __hip_atomic_load(&g_bcast[lane24 * LSTRIDE], __ATOMIC_RELAXED,
                                 __HIP_MEMORY_SCOPE_AGENT);

    if (bk >= NEDGE) {
        // ==================== dedicated phase1 block: c = bk - NEDGE ====================
        const int c = bk - NEDGE;
        const int p = tid >> 4;          // p in [0,12) for tid<192
        const int b = tid & 15;          // b in [0,16)
        float g1v = 0.f, b1v = 0.f, g2v = 0.f, b2v = 0.f, baggv = 0.f;
        if (tid < NP * NP) wagg[tid] = Wagg[tid];
        if (tid < 192) {
            g1v = g1[c * NP + p]; b1v = b1[c * NP + p];
            g2v = g2[c * NP + p]; b2v = b2[c * NP + p];
            baggv = bagg[p];
        }
        // BN0 for this channel -> xnL; write 'first' slice to out (harness-only,
        // never read cross-block -> normal store, flushed at kernel end)
        if (tid < NT) {
            const int tt = tid;
            float v[NB]; float sum = 0.f;
#pragma unroll
            for (int bb = 0; bb < NB; bb++) { v[bb] = x[bb * CT + c * NT + tt]; sum += v[bb]; }
            float mu = sum * (1.f / NB);
            float var = 0.f;
#pragma unroll
            for (int bb = 0; bb < NB; bb++) { float d = v[bb] - mu; var = fmaf(d, d, var); }
            var *= (1.f / NB);
            float rs = rsqrtf(var + 1e-5f);
            float gg = g0[c * NT + tt], bbv = b0[c * NT + tt];
#pragma unroll
            for (int bb = 0; bb < NB; bb++) {
                float y = (v[bb] - mu) * rs * gg + bbv;
                xnL[bb][tt] = y;
                if (tt < NP) out[(bb * NC + c) * NT + tt] = y;
            }
        }
        __syncthreads();

        for (int s = 0; s < STEPS; s++) {
            if (s > 0) {
                if (tid == 0) bar_wait(lane24, gen0 + 2 * s);   // A(s-1)
                __syncthreads();
            }
            if (tid < 192) {
                float v = (s == 0) ? xnL[b][p]
                                   : ldg_llc(&out[(b * NC + c) * NT + NP * s + p]);
                float s1 = v;
#pragma unroll
                for (int off = 1; off < 16; off <<= 1) s1 += __shfl_xor(s1, off);
                float mu = s1 * (1.f / NB);
                float d  = v - mu;
                float q  = d * d;
#pragma unroll
                for (int off = 1; off < 16; off <<= 1) q += __shfl_xor(q, off);
                float var = q * (1.f / NB);
                float inp = d * rsqrtf(var + 1e-5f) * g1v + b1v;
                shB[b * NP + p] = inp;
            }
            __syncthreads();
            if (tid < 192) {
                float acc = baggv;
#pragma unroll
                for (int pp = 0; pp < NP; pp++)
                    acc = fmaf(shB[b * NP + pp], wagg[p * NP + pp], acc);
                float res = gelu_exact(acc) + xnL[b][NP + NP * s + p];
                stg_llc(&res_ws[(b * NC + c) * NP + p], res);
                float s2 = res;
#pragma unroll
                for (int off = 1; off < 16; off <<= 1) s2 += __shfl_xor(s2, off);
                float mu2 = s2 * (1.f / NB);
                float d2  = res - mu2;
                float q2  = d2 * d2;
#pragma unroll
                for (int off = 1; off < 16; off <<= 1) q2 += __shfl_xor(q2, off);
                float var2 = q2 * (1.f / NB);
                float t = d2 * rsqrtf(var2 + 1e-5f) * g2v + b2v;
                stg_llc(&t_ws[(b * NP + p) * NC + c], t);    // t[b][p][c]
            }
            __syncthreads();   // drains all waves' vmcnt -> stores complete at LLC
            if (tid == 0)
                tree_arrive(g_subB, &g_rootB, lane24,
                            s == 0 ? 26u : 2u, gen0 + 2 * s + 1);   // B(s)
        }
        return;
    }

    // ==================== edge block ====================
    if (tid < NFF) coef[tid] = make_float4(W1[2 * tid], W1[2 * tid + 1], bm1[tid], W2[tid]);
    const float wmsg0 = wmsg[0], bmsg0 = bmsg[0];

    const int w    = bk * 4 + (tid >> 6);       // wave id in [0,2304)
    const int lane = tid & 63;
    const int rl   = lane >> 4;                 // row within the wave's 4-row group
    const int jg   = lane & 15;                 // j-lane in [0,16)
    const int e_bp = w / NP;                    // (b,p) pair in [0,192)
    const int e_i  = (w - e_bp * NP) * 4 + rl;  // i in [0,48)
    const int e_b  = e_bp / NP, e_p = e_bp - e_b * NP;
    const float* tb = t_ws + e_bp * NC;
    const int outIdxBase = (e_b * NC + e_i) * NT + e_p;
    const int resIdx     = (e_b * NC + e_i) * NP + e_p;

    __syncthreads();
    if (tid == 0)
        tree_arrive(g_subB, &g_rootB, lane24, 26u, gen0 + 1);  // entry into B(0)

    for (int s = 0; s < STEPS; s++) {
        if (tid == 0) bar_wait(lane24, gen0 + 2 * s + 1);  // B(s): t_ws ready
        __syncthreads();

        float zi  = ldg_llc(&tb[e_i]);
        float zj0 = ldg_llc(&tb[jg]);
        float zj1 = ldg_llc(&tb[jg + 16]);
        float zj2 = ldg_llc(&tb[jg + 32]);
        float e0 = 0.f, e1 = 0.f, e2 = 0.f;
#pragma unroll 8
        for (int ff = 0; ff < NFF; ff++) {
            float4 cf = coef[ff];
            float base = fmaf(cf.x, zi, cf.z);
            e0 = fmaf(gelu_exact(fmaf(cf.y, zj0, base)), cf.w, e0);
            e1 = fmaf(gelu_exact(fmaf(cf.y, zj1, base)), cf.w, e1);
            e2 = fmaf(gelu_exact(fmaf(cf.y, zj2, base)), cf.w, e2);
        }
        // local sort-3 (value desc, index asc)
        float v0 = e0, v1 = e1, v2 = e2;
        int   j0 = jg, j1 = jg + 16, j2 = jg + 32;
        CSWAP(v0, j0, v1, j1);
        CSWAP(v1, j1, v2, j2);
        CSWAP(v0, j0, v1, j1);
        // butterfly merge across the 16 j-lanes -> every lane holds row top-3
#pragma unroll
        for (int off = 1; off < 16; off <<= 1) {
            float o0 = __shfl_xor(v0, off), o1 = __shfl_xor(v1, off), o2 = __shfl_xor(v2, off);
            int   q0 = __shfl_xor(j0, off), q1 = __shfl_xor(j1, off), q2 = __shfl_xor(j2, off);
            INSERT3(o0, q0);
            INSERT3(o1, q1);
            INSERT3(o2, q2);
        }
        // softmax over the 3 selected (max = v0); znew = wmsg*avg(t) + bmsg
        const float L2E = 1.4426950408889634f;
        float ww1 = __builtin_amdgcn_exp2f((v1 - v0) * L2E);
        float ww2 = __builtin_amdgcn_exp2f((v2 - v0) * L2E);
        float wsum = 1.f + ww1 + ww2;
        float tsum = fmaf(ww2, ldg_llc(&tb[j2]),
                          fmaf(ww1, ldg_llc(&tb[j1]), ldg_llc(&tb[j0])));
        float znew = fmaf(wmsg0, tsum / wsum, bmsg0);
        if (jg == 0) {
            float res = ldg_llc(&res_ws[resIdx]);
            stg_llc(&out[outIdxBase + NP * (s + 1)], fmaf(0.5f, znew, res)); // ALPHA=0.5
        }

        if (s < STEPS - 1) {
            __syncthreads();   // drains all waves' vmcnt -> out-stores at LLC
            if (tid == 0)
                tree_arrive(g_subA, &g_rootA, lane24, 24u, gen0 + 2 * s + 2); // A(s)
        }
    }
}

extern "C" void kernel_launch(void* const* d_in, const int* in_sizes, int n_in,
                              void* d_out, int out_size, void* d_ws, size_t ws_size,
                              hipStream_t stream)
{
    const float* x    = (const float*)d_in[0];
    const float* g0   = (const float*)d_in[1];
    const float* b0   = (const float*)d_in[2];
    const float* g1   = (const float*)d_in[3];
    const float* b1   = (const float*)d_in[4];
    const float* g2   = (const float*)d_in[5];
    const float* b2   = (const float*)d_in[6];
    const float* Wagg = (const float*)d_in[7];
    const float* bagg = (const float*)d_in[8];
    const float* W1   = (const float*)d_in[9];
    const float* bm1  = (const float*)d_in[10];
    const float* W2   = (const float*)d_in[11];
    // d_in[12] = bm2: uniform shift of e -> invariant under top-k & softmax; unused
    const float* wmsg = (const float*)d_in[13];
    const float* bmsg = (const float*)d_in[14];
    float* out = (float*)d_out;

    float* t_ws   = (float*)d_ws;            // 9216 floats
    float* res_ws = t_ws + (NB * NP * NC);   // 9216 floats

    fused_kernel<<<dim3(NBLK), dim3(NTHR), 0, stream>>>(
        x, g0, b0, g1, b1, g2, b2, Wagg, bagg, W1, bm1, W2, wmsg, bmsg,
        t_ws, res_ws, out);
}